// Round 7
// baseline (1510.167 us; speedup 1.0000x reference)
//
#include <hip/hip_runtime.h>

// GRU via token->gi table + materialized gi stream:
//   A) f32->bf16 converts.
//   B) tbl[v][g] = W_ih@emb[v] + b_ih + (g<512 ? b_hh : 0), bf16 [32000][768], 49 MB.
//   C) gi_mat: 256-CU gather-copy, table rows -> swizzled gi stream [t][blk32][24576B]
//      (identical byte format to R3's proven consumer).
//   D) gru_rec: R3-proven body. 32 blocks x 512 thr; W_hh register-resident; 4-deep
//      linear-stream LDS ring via global_load_lds; counted vmcnt(6/3/0); 1 barrier/step.
// ws-adaptive chunking (h crosses chunks via d_out, f32 exact).

typedef unsigned short ushort_t;
typedef __attribute__((ext_vector_type(8))) short short8;
typedef __attribute__((ext_vector_type(4))) float float4_;
typedef __attribute__((ext_vector_type(4))) unsigned short ushort4_;
typedef __attribute__((ext_vector_type(2))) unsigned int uint2_;
typedef __attribute__((ext_vector_type(4))) int int4_;

#define VOCAB 32000
#define EMB 128
#define HID 256
#define G3 768
#define TT 512
#define SLOT 786432      // gi bytes per timestep: 512*768*2
#define BLK_BYTES 24576  // gi bytes per (t, 16-batch blk)
#define TBL_OFF 8781824  // after emb16+Wih16+Whh16
#define GIC_OFF 57933824 // after table (49,152,000 B)

__device__ __forceinline__ float b2f(ushort_t u) {
  return __uint_as_float(((unsigned)u) << 16);
}
__device__ __forceinline__ ushort_t f2b(float f) {
  unsigned u = __float_as_uint(f);
  return (ushort_t)((u + 0x7FFFu + ((u >> 16) & 1u)) >> 16);
}
__device__ __forceinline__ short8 ld8(const ushort_t* p) { return *(const short8*)p; }
__device__ __forceinline__ void gld_lds16(const void* g, void* l) {
  __builtin_amdgcn_global_load_lds((const __attribute__((address_space(1))) void*)g,
                                   (__attribute__((address_space(3))) void*)l, 16, 0, 0);
}
// swizzled byte offset of (batch-local bl, byte-col c) inside a 24576-B tile
__device__ __forceinline__ int gi_byte(int bl, int c) {
  return ((bl * 1536) + c) ^ ((bl & 7) << 4);
}

// ---------------- Phase A ----------------
__global__ void cvt_bf16_k(const float* __restrict__ s, ushort_t* __restrict__ d, int n4) {
  int i = blockIdx.x * blockDim.x + threadIdx.x;
  int stride = gridDim.x * blockDim.x;
  for (; i < n4; i += stride) {
    float4_ v = ((const float4_*)s)[i];
    ushort4_ o;
    o.x = f2b(v.x); o.y = f2b(v.y); o.z = f2b(v.z); o.w = f2b(v.w);
    ((ushort4_*)d)[i] = o;
  }
}

// ---------------- Phase B: token->gi table (2000 blocks x 256 thr) ----------------
__global__ __launch_bounds__(256) void tbl_gemm(
    const ushort_t* __restrict__ emb16, const ushort_t* __restrict__ Wih16,
    const float* __restrict__ bih, const float* __restrict__ bhh,
    char* __restrict__ tb_out) {
  __shared__ float cbs[G3];
  __shared__ alignas(16) char img[16 * 1552];
  const int tid = threadIdx.x;
  for (int i = tid; i < G3; i += 256) cbs[i] = bih[i] + (i < 512 ? bhh[i] : 0.f);
  const int lane = tid & 63, w = tid >> 6;
  const int bl = lane & 15, kg = lane >> 4;
  const int v0 = blockIdx.x * 16;

  short8 bfr[4];
#pragma unroll
  for (int kt = 0; kt < 4; ++kt)
    bfr[kt] = ld8(emb16 + (size_t)(v0 + bl) * EMB + kt * 32 + kg * 8);
  __syncthreads();

#pragma unroll 1
  for (int mi = 0; mi < 12; ++mi) {
    int mt = w * 12 + mi;
    short8 af[4];
#pragma unroll
    for (int kt = 0; kt < 4; ++kt)
      af[kt] = ld8(Wih16 + (mt * 16 + bl) * EMB + kt * 32 + kg * 8);
    float4_ acc = {0.f, 0.f, 0.f, 0.f};
#pragma unroll
    for (int kt = 0; kt < 4; ++kt)
      acc = __builtin_amdgcn_mfma_f32_16x16x32_bf16(af[kt], bfr[kt], acc, 0, 0, 0);
    int g0 = mt * 16 + kg * 4;
    ushort4_ o;
#pragma unroll
    for (int r = 0; r < 4; ++r) o[r] = f2b(acc[r] + cbs[g0 + r]);
    *(ushort4_*)(img + bl * 1552 + mt * 32 + kg * 8) = o;
  }
  __syncthreads();

#pragma unroll
  for (int c = 0; c < 6; ++c) {
    int p = c * 4096 + tid * 16;
    int q = p >> 9;
    int row = (q * 21846) >> 16;  // q/3 for q<48
    int off = p - row * 1536;
    float4_ v = *(const float4_*)(img + row * 1552 + off);
    *(float4_*)(tb_out + (size_t)(v0 + row) * 1536 + off) = v;
  }
}

// ---------------- Phase C: gi materializer (device-scale gather-copy) ----------------
// grid = ntg*32 blocks x 256 thr; block (tg, blk) copies 4 timesteps' 24KB tiles.
__global__ __launch_bounds__(256) void gi_mat(
    const int* __restrict__ x, const char* __restrict__ tbl,
    char* __restrict__ gic, int tbase, int Cc) {
  __shared__ int toks[64];
  const int tg = blockIdx.x >> 5, blk = blockIdx.x & 31;
  const int tid = threadIdx.x;
  if (tid < 64) {
    int j = tid >> 4, row = tid & 15;
    int tt = 4 * tg + j;
    toks[tid] = (tt < Cc) ? x[(blk * 16 + row) * TT + tbase + tt] : 0;
  }
  __syncthreads();
  const int row = tid >> 4;
  const int c0 = (tid & 15) * 16;
  const int rs = (row & 7) << 4;
#pragma unroll
  for (int j = 0; j < 4; ++j) {
    int tt = 4 * tg + j;
    if (tt < Cc) {
      const char* src = tbl + (size_t)toks[j * 16 + row] * 1536u + c0;
      char* dst = gic + (size_t)tt * SLOT + (size_t)blk * BLK_BYTES;
#pragma unroll
      for (int ii = 0; ii < 6; ++ii) {
        float4_ v = *(const float4_*)(src + ii * 256);
        *(float4_*)(dst + ((row * 1536 + c0 + ii * 256) ^ rs)) = v;
      }
    }
  }
}

// ---------------- Phase D: recurrence (R3-proven body) ----------------
// LDS: ring[4][24576] @0 | h[2][8192] @98304 = 114688 B
__global__ __launch_bounds__(512, 2) void gru_rec(
    const ushort_t* __restrict__ Whh16, const char* __restrict__ gic,
    const float* __restrict__ bhh, float* __restrict__ out, int t0, int C) {
  __shared__ alignas(16) char smem[114688];

  const int tid = threadIdx.x, lane = tid & 63, w = tid >> 6;
  const int bl = lane & 15, kg = lane >> 4;
  const int b0 = blockIdx.x * 16;
  const char* gblk = gic + (size_t)blockIdx.x * BLK_BYTES;

  if (t0 == 0) {
    int4_ z4 = {0, 0, 0, 0};
    *(int4_*)(smem + 98304 + tid * 16) = z4;
  } else {
    for (int i = tid; i < 16 * HID; i += 512) {
      int b = i >> 8, k = i & 255;
      *(ushort_t*)(smem + 98304 + (((b << 9) + 2 * k) ^ ((b & 7) << 4))) =
          f2b(out[(size_t)(b0 + b) * HID + k]);
    }
  }

  // W_hh fragments, register/AGPR-resident.
  short8 wf[2][3][8];
#pragma unroll
  for (int i = 0; i < 2; ++i)
#pragma unroll
    for (int q = 0; q < 3; ++q) {
      int g = (w + 8 * i + 16 * q) * 16 + bl;
#pragma unroll
      for (int kt = 0; kt < 8; ++kt)
        wf[i][q][kt] = ld8(Whh16 + (size_t)g * HID + kt * 32 + kg * 8);
    }

  float4_ bhn[2];
  float hreg[2][4];
#pragma unroll
  for (int i = 0; i < 2; ++i) {
    bhn[i] = *(const float4_*)&bhh[512 + (w + 8 * i) * 16 + kg * 4];
    if (t0 == 0) {
#pragma unroll
      for (int r = 0; r < 4; ++r) hreg[i][r] = 0.f;
    } else {
      float4_ v = *(const float4_*)&out[(size_t)(b0 + bl) * HID + (w + 8 * i) * 16 + kg * 4];
#pragma unroll
      for (int r = 0; r < 4; ++r) hreg[i][r] = v[r];
    }
  }

  // drain prologue vmem + make h visible, then start the pipeline
  asm volatile("s_waitcnt vmcnt(0) lgkmcnt(0)" ::: "memory");
  __builtin_amdgcn_s_barrier();
  __builtin_amdgcn_sched_barrier(0);

#pragma unroll
  for (int tau = 0; tau < 3; ++tau) {
    if (tau < C) {
      const char* src = gblk + (size_t)tau * SLOT + (w * 3) * 1024 + lane * 16;
      char* dst = smem + tau * 24576 + (w * 3) * 1024;
#pragma unroll
      for (int ii = 0; ii < 3; ++ii) gld_lds16(src + ii * 1024, dst + ii * 1024);
    }
  }

#pragma unroll 1
  for (int t = 0; t < C; ++t) {
    int rem = C - 1 - t;
    if (rem >= 2)
      asm volatile("s_waitcnt vmcnt(6) lgkmcnt(0)" ::: "memory");
    else if (rem == 1)
      asm volatile("s_waitcnt vmcnt(3) lgkmcnt(0)" ::: "memory");
    else
      asm volatile("s_waitcnt vmcnt(0) lgkmcnt(0)" ::: "memory");
    __builtin_amdgcn_s_barrier();
    __builtin_amdgcn_sched_barrier(0);

    const int slot = t & 3, cur = t & 1, nxt = cur ^ 1;
    if (t + 3 < C) {
      const char* src = gblk + (size_t)(t + 3) * SLOT + (w * 3) * 1024 + lane * 16;
      char* dst = smem + ((t + 3) & 3) * 24576 + (w * 3) * 1024;
#pragma unroll
      for (int ii = 0; ii < 3; ++ii) gld_lds16(src + ii * 1024, dst + ii * 1024);
    }

    const char* gtile = smem + slot * 24576;

    float4_ acc[2][3];
#pragma unroll
    for (int i = 0; i < 2; ++i) {
#pragma unroll
      for (int q = 0; q < 2; ++q) {
        int byte8 = gi_byte(bl, 32 * (w + 8 * i + 16 * q) + 8 * kg);
        ushort4_ v = *(const ushort4_*)(gtile + byte8);
#pragma unroll
        for (int r = 0; r < 4; ++r) acc[i][q][r] = b2f(v[r]);
      }
      acc[i][2] = bhn[i];
    }

#pragma unroll
    for (int kt = 0; kt < 8; ++kt) {
      int byteoff = ((bl * 512) + kt * 64 + kg * 16) ^ ((bl & 7) << 4);
      short8 bf = *(const short8*)(smem + 98304 + cur * 8192 + byteoff);
#pragma unroll
      for (int i = 0; i < 2; ++i)
#pragma unroll
        for (int q = 0; q < 3; ++q)
          acc[i][q] = __builtin_amdgcn_mfma_f32_16x16x32_bf16(wf[i][q][kt], bf, acc[i][q], 0, 0, 0);
    }

#pragma unroll
    for (int i = 0; i < 2; ++i) {
      int byte8n = gi_byte(bl, 32 * (32 + w + 8 * i) + 8 * kg);
      ushort4_ gv = *(const ushort4_*)(gtile + byte8n);
#pragma unroll
      for (int r = 0; r < 4; ++r) {
        float rr = __builtin_amdgcn_rcpf(1.f + __expf(-acc[i][0][r]));
        float zz = __builtin_amdgcn_rcpf(1.f + __expf(-acc[i][1][r]));
        float y = b2f(gv[r]) + rr * acc[i][2][r];
        float nn = 1.f - 2.f * __builtin_amdgcn_rcpf(1.f + __expf(2.f * y));
        hreg[i][r] = (1.f - zz) * nn + zz * hreg[i][r];
      }
      int byte0 = (bl * 512 + ((w + 8 * i) * 16 + kg * 4) * 2) ^ ((bl & 7) << 4);
      uint2_ hv;
      hv.x = (unsigned)f2b(hreg[i][0]) | ((unsigned)f2b(hreg[i][1]) << 16);
      hv.y = (unsigned)f2b(hreg[i][2]) | ((unsigned)f2b(hreg[i][3]) << 16);
      *(uint2_*)(smem + 98304 + nxt * 8192 + byte0) = hv;
    }
  }

#pragma unroll
  for (int i = 0; i < 2; ++i) {
    float4_ v = {hreg[i][0], hreg[i][1], hreg[i][2], hreg[i][3]};
    *(float4_*)&out[(size_t)(b0 + bl) * HID + (w + 8 * i) * 16 + kg * 4] = v;
  }
}

extern "C" void kernel_launch(void* const* d_in, const int* in_sizes, int n_in,
                              void* d_out, int out_size, void* d_ws, size_t ws_size,
                              hipStream_t stream) {
  const int* x = (const int*)d_in[0];
  const float* emb = (const float*)d_in[1];
  const float* Wih = (const float*)d_in[2];
  const float* Whh = (const float*)d_in[3];
  const float* bih = (const float*)d_in[4];
  const float* bhh = (const float*)d_in[5];
  float* out = (float*)d_out;

  char* ws = (char*)d_ws;
  ushort_t* emb16 = (ushort_t*)ws;                 // 8,192,000 B
  ushort_t* Wih16 = (ushort_t*)(ws + 8192000);     //   196,608 B
  ushort_t* Whh16 = (ushort_t*)(ws + 8388608);     //   393,216 B
  char* tbl = ws + TBL_OFF;                        // 49,152,000 B token->gi table
  char* gic = ws + GIC_OFF;                        // gi stream ring, C slots

  size_t avail = ws_size > (size_t)GIC_OFF ? ws_size - (size_t)GIC_OFF : 0;
  int C = (int)(avail / (size_t)SLOT);
  if (C > TT) C = TT;
  if (C < 1) C = 1;

  cvt_bf16_k<<<1024, 256, 0, stream>>>(emb, emb16, (VOCAB * EMB) / 4);
  cvt_bf16_k<<<96, 256, 0, stream>>>(Wih, Wih16, (G3 * EMB) / 4);
  cvt_bf16_k<<<192, 256, 0, stream>>>(Whh, Whh16, (G3 * HID) / 4);
  tbl_gemm<<<2000, 256, 0, stream>>>(emb16, Wih16, bih, bhh, tbl);

  for (int t0 = 0; t0 < TT; t0 += C) {
    int Cc = TT - t0 < C ? TT - t0 : C;
    int ntg = (Cc + 3) / 4;
    gi_mat<<<32 * ntg, 256, 0, stream>>>(x, tbl, gic, t0, Cc);
    gru_rec<<<32, 512, 0, stream>>>(Whh16, gic, bhh, out, t0, Cc);
  }
}